// Round 10
// baseline (184.597 us; speedup 1.0000x reference)
//
#include <hip/hip_runtime.h>
#include <math.h>

typedef _Float16 half8 __attribute__((ext_vector_type(8)));
typedef __fp16 fp16x2 __attribute__((ext_vector_type(2)));
typedef float floatx4 __attribute__((ext_vector_type(4)));
typedef float floatx2 __attribute__((ext_vector_type(2)));

constexpr int IN_DIM = 36;
constexpr int BLOCKS = 2048;
// R16 channel map (prep-side remaps; zxbcdt source channels):
//   z-tile u (fid 2u):   tile-row c = z ch  8*(c>>2) + 4*(u&1) + (c&3) + 32*(u>>1)
//   xh-tile u (fid 8+2u): same + 64
//   => after GEMM1, lane (c,q) holds y chs {8q..8q+7} (t=0,1) and
//      {32+8q..+7} (t=2,3)  ==  GEMM2 By0/By1 IN REGISTER (no LDS hop).
//      Head of every ch in tile t for lane q: q + 4*(t>=2).
//   tile 8 (B/C interleave, R15): row c = ((c&1)?136:128) + 2*(c>>2) + ((c>>1)&1)
//   tile 9 (dt):          row c = 144 + (c>>2) + 4*((c&3)>>1)
//      => lane q: acc9[0] = dt head q, acc9[2] = dt head q+4.

__device__ __forceinline__ float fast_rcp(float v) { return __builtin_amdgcn_rcpf(v); }
__device__ __forceinline__ float silu_f(float v) { return v * fast_rcp(1.0f + __expf(-v)); }
__device__ __forceinline__ float softplus_f(float v) {
    return fmaxf(v, 0.0f) + __logf(1.0f + __expf(-fabsf(v)));
}
__device__ __forceinline__ float pk2f(float a, float b) {
    fp16x2 p = __builtin_amdgcn_cvt_pkrtz(a, b);   // v_cvt_pkrtz_f16_f32
    return __builtin_bit_cast(float, p);
}

// ---- prep: 24 fp16 A-operand fragments into d_ws (one block per fragment) ----
// fid 0..19: GEMM1 A = Wc^T (Wc[k][ch] = sum_m f_out_w[m][k]*in_proj_w[ch][m],
//   conv_w folded for ch in [64,144)). Ghost k=36 carries the fully-fused bias.
// fid 20..23: GEMM2 A = out_proj_w[m][k] * norm_w[k] (norm fold).
extern "C" __global__ void __launch_bounds__(64)
prep_kernel(const float* __restrict__ f_out_w, const float* __restrict__ f_out_b,
            const float* __restrict__ in_proj_w, const float* __restrict__ conv_w,
            const float* __restrict__ conv_b, const float* __restrict__ dt_bias,
            const float* __restrict__ norm_w, const float* __restrict__ out_proj_w,
            void* __restrict__ ws) {
    const int fid = blockIdx.x;
    const int L = threadIdx.x;
    const int c = L & 15, q = L >> 4;
    unsigned short* fr = (unsigned short*)ws;
    for (int j = 0; j < 8; ++j) {
        float val = 0.f;
        if (fid < 20) {
            const int t = fid >> 1, ks = fid & 1;
            int m;
            if (t < 8) {                            // z (t<4) / xh (t>=4) remap
                const int u = t & 3;
                m = ((t < 4) ? 0 : 64) +
                    8 * (c >> 2) + 4 * (u & 1) + (c & 3) + 32 * (u >> 1);
            } else if (t == 8) {                    // B/C interleave remap (R15)
                m = ((c & 1) ? 136 : 128) + 2 * (c >> 2) + ((c >> 1) & 1);
            } else {                                // dt: heads {q, q+4} per lane
                m = 144 + (c >> 2) + 4 * ((c & 3) >> 1);
            }
            const int k = ks * 32 + q * 8 + j;      // feature
            if (m < 152) {
                if (k < IN_DIM) {
                    float acc = 0.f;
                    for (int mm = 0; mm < 32; ++mm)
                        acc += f_out_w[mm * IN_DIM + k] * in_proj_w[m * 32 + mm];
                    if (m >= 64 && m < 144) acc *= conv_w[(m - 64) * 2 + 1];
                    val = acc;
                } else if (k == IN_DIM) {           // ghost-feature bias slot
                    float acc = 0.f;
                    for (int mm = 0; mm < 32; ++mm)
                        acc += f_out_b[mm] * in_proj_w[m * 32 + mm];
                    if (m >= 64 && m < 144)      val = acc * conv_w[(m - 64) * 2 + 1] + conv_b[m - 64];
                    else if (m >= 144)           val = acc + dt_bias[m - 144];
                    else                         val = acc;
                }
            }
        } else {
            const int mt = (fid - 20) >> 1, ks = (fid - 20) & 1;
            const int m = mt * 16 + c;              // out channel (<32)
            const int k = ks * 32 + q * 8 + j;      // y channel (<64)
            val = out_proj_w[m * 64 + k] * norm_w[k];
        }
        _Float16 h = (_Float16)val;
        fr[fid * 512 + L * 8 + j] = __builtin_bit_cast(unsigned short, h);
    }
}

// ---- main: transposed GEMMs; lane (c,q) owns row c of its 16-row tile ----
// R17 = R16 body (y-in-register GEMM2, lane-local bc/scale, 0 bank conflicts,
// LDS 24.5KB) with ONE change: __launch_bounds__(256, 4). R13/R15/R16 proved
// the wall is stall time (VALU 45% + MFMA 10%, rest idle at ~2 waves/SIMD);
// every chain-shortening lever was neutral. The R16 body's peak live set
// (~110 unified regs by audit) should fit the 128-reg budget 4 waves/SIMD
// needs — unlike R8/R10 whose bodies carried ldsY + 40-reg acc + hoisted A3.
// Spill tripwire: FETCH must stay ~37MB, WRITE ~65.5MB. If they balloon,
// this door is closed for good and (256,3) is the structural ceiling.
extern "C" __global__ void __launch_bounds__(256, 4)
mamba_mfma_kernel(const float* __restrict__ x,
                  const float* __restrict__ D_skip,
                  const void* __restrict__ ws,
                  float* __restrict__ out,
                  int tiles_per_wave) {
    __shared__ float4 ldsW[1536];                  // 24 KiB: 24 A-fragments, 16B-aligned
    const int lane = threadIdx.x & 63;
    const int wv   = threadIdx.x >> 6;
    const int c = lane & 15, q = lane >> 4;

    // cooperative stage of all 24 fragments: 24576 B / 256 thr = 6 float4 each
    {
        const float4* src = (const float4*)ws;
#pragma unroll
        for (int i = 0; i < 6; ++i)
            ldsW[threadIdx.x + 256 * i] = src[threadIdx.x + 256 * i];
    }

    // D_skip for this lane's two heads (q and q+4)
    const float dsk0 = D_skip[q];
    const float dsk1 = D_skip[q + 4];

    const long rowBase = (long)(blockIdx.x * 4 + wv) * tiles_per_wave * 16;
    const float* xrow = x + (rowBase + c) * (long)IN_DIM;

    float4 xa, xb, xct;
    {
        const float* p = xrow + q * 8;
        xa = *(const float4*)p;
        xb = *(const float4*)(p + 4);
        xct = (q == 0) ? *(const float4*)(xrow + 32) : make_float4(0.f, 0.f, 0.f, 0.f);
    }

    __syncthreads();                               // weights resident in LDS
    const char* Wb = (const char*)ldsW;

#pragma unroll 1
    for (int tile = 0; tile < tiles_per_wave; ++tile) {
        float4 na = xa, nb = xb, nc2 = xct;
        if (tile + 1 < tiles_per_wave) {
            const float* p = xrow + (size_t)(tile + 1) * 16 * IN_DIM + q * 8;
            na = *(const float4*)p;
            nb = *(const float4*)(p + 4);
            if (q == 0) nc2 = *(const float4*)(xrow + (size_t)(tile + 1) * 16 * IN_DIM + 32);
        }

        // B-operand from x, packed with v_cvt_pkrtz (2 floats/op); bit_cast keeps
        // everything in registers (unions here caused scratch spills in R6).
        float4 t0, t1;
        t0.x = pk2f(xa.x, xa.y);
        t0.y = pk2f(xa.z, xa.w);
        t0.z = pk2f(xb.x, xb.y);
        t0.w = pk2f(xb.z, xb.w);
        t1.x = pk2f(xct.x, xct.y);                  // xct already 0 for q!=0
        t1.y = pk2f(xct.z, xct.w);
        t1.z = (q == 0) ? pk2f(1.0f, 0.0f) : 0.0f;  // ghost feature -> bias
        t1.w = 0.0f;
        const half8 Bx0 = __builtin_bit_cast(half8, t0);
        const half8 Bx1 = __builtin_bit_cast(half8, t1);

        // ---- tiles 8 (B/C interleaved) and 9 (dt remapped) first ----
        floatx4 acc8, acc9;
        {
            const half8 c80 = *(const half8*)(Wb + (size_t)(16 * 64 + lane) * 16);
            const half8 c81 = *(const half8*)(Wb + (size_t)(17 * 64 + lane) * 16);
            const half8 c90 = *(const half8*)(Wb + (size_t)(18 * 64 + lane) * 16);
            const half8 c91 = *(const half8*)(Wb + (size_t)(19 * 64 + lane) * 16);
            floatx4 z4 = {0.f, 0.f, 0.f, 0.f};
            acc8 = __builtin_amdgcn_mfma_f32_16x16x32_f16(c80, Bx0, z4, 0, 0, 0);
            acc8 = __builtin_amdgcn_mfma_f32_16x16x32_f16(c81, Bx1, acc8, 0, 0, 0);
            acc9 = __builtin_amdgcn_mfma_f32_16x16x32_f16(c90, Bx0, z4, 0, 0, 0);
            acc9 = __builtin_amdgcn_mfma_f32_16x16x32_f16(c91, Bx1, acc9, 0, 0, 0);
        }

        // bc: in-lane silu(B[s])*silu(C[s]) pairs (s = 2q + {0,1}), then
        // xor16 + xor32 sum over the 4 q-lanes -> bc in ALL lanes. 2 shuffles.
        float part;
        {
            const float b0 = acc8[0], c0 = acc8[1], b1 = acc8[2], c1 = acc8[3];
            const float d0 = (1.0f + __expf(-b0)) * (1.0f + __expf(-c0));
            const float d1 = (1.0f + __expf(-b1)) * (1.0f + __expf(-c1));
            part = b0 * c0 * fast_rcp(d0) + b1 * c1 * fast_rcp(d1);
        }
        const float h1 = part + __shfl_xor(part, 16, 64);
        const float bc = h1 + __shfl_xor(h1, 32, 64);

        // per-head scale, lane-local: acc9[0] = dt head q, acc9[2] = head q+4
        const float sclH0 = __builtin_fmaf(softplus_f(acc9[0]), bc, dsk0);
        const float sclH1 = __builtin_fmaf(softplus_f(acc9[2]), bc, dsk1);

        // ---- z/xh pairs: 4 MFMAs per t, consumed immediately into By ----
        // tile t supplies y chs {8q + 4*(t&1) + r + 32*(t>>1)} (head q+4*(t>>1))
        // -> packed pk2f pairs land DIRECTLY in By0 (t=0,1) / By1 (t=2,3).
        float4 by0f, by1f;
        float ssum = 0.f;
#pragma unroll
        for (int t = 0; t < 4; ++t) {
            const half8 cz0 = *(const half8*)(Wb + (size_t)((t * 2 + 0) * 64 + lane) * 16);
            const half8 cz1 = *(const half8*)(Wb + (size_t)((t * 2 + 1) * 64 + lane) * 16);
            const half8 cx0 = *(const half8*)(Wb + (size_t)(((t + 4) * 2 + 0) * 64 + lane) * 16);
            const half8 cx1 = *(const half8*)(Wb + (size_t)(((t + 4) * 2 + 1) * 64 + lane) * 16);
            floatx4 z4 = {0.f, 0.f, 0.f, 0.f};
            floatx4 az = __builtin_amdgcn_mfma_f32_16x16x32_f16(cz0, Bx0, z4, 0, 0, 0);
            az = __builtin_amdgcn_mfma_f32_16x16x32_f16(cz1, Bx1, az, 0, 0, 0);
            floatx4 ax = __builtin_amdgcn_mfma_f32_16x16x32_f16(cx0, Bx0, z4, 0, 0, 0);
            ax = __builtin_amdgcn_mfma_f32_16x16x32_f16(cx1, Bx1, ax, 0, 0, 0);

            const float scl = (t < 2) ? sclH0 : sclH1;
            float v[4];
#pragma unroll
            for (int r = 0; r < 4; ++r) {
                const float zr = az[r], xh = ax[r];
                const float den = (1.0f + __expf(-zr)) * (1.0f + __expf(-xh));
                v[r] = zr * xh * scl * fast_rcp(den);
                ssum = __builtin_fmaf(v[r], v[r], ssum);
            }
            const float plo = pk2f(v[0], v[1]);
            const float phi = pk2f(v[2], v[3]);
            if (t == 0)      { by0f.x = plo; by0f.y = phi; }
            else if (t == 1) { by0f.z = plo; by0f.w = phi; }
            else if (t == 2) { by1f.x = plo; by1f.y = phi; }
            else             { by1f.z = plo; by1f.w = phi; }
        }
        const half8 By0 = __builtin_bit_cast(half8, by0f);
        const half8 By1 = __builtin_bit_cast(half8, by1f);

        // GEMM2 A-fragments (weights) + MFMAs — independent of the ssum chain,
        // so they overlap the reduction shuffles below.
        const half8 A300 = *(const half8*)(Wb + (size_t)(20 * 64 + lane) * 16);
        const half8 A301 = *(const half8*)(Wb + (size_t)(21 * 64 + lane) * 16);
        const half8 A310 = *(const half8*)(Wb + (size_t)(22 * 64 + lane) * 16);
        const half8 A311 = *(const half8*)(Wb + (size_t)(23 * 64 + lane) * 16);

        floatx4 z4 = {0.f, 0.f, 0.f, 0.f};
        floatx4 lg0 = __builtin_amdgcn_mfma_f32_16x16x32_f16(A300, By0, z4, 0, 0, 0);
        lg0 = __builtin_amdgcn_mfma_f32_16x16x32_f16(A301, By1, lg0, 0, 0, 0);
        floatx4 lg1 = __builtin_amdgcn_mfma_f32_16x16x32_f16(A310, By0, z4, 0, 0, 0);
        lg1 = __builtin_amdgcn_mfma_f32_16x16x32_f16(A311, By1, lg1, 0, 0, 0);

        float ssr = ssum + __shfl_xor(ssum, 16, 64);
        ssr += __shfl_xor(ssr, 32, 64);
        const float rs = __builtin_amdgcn_rsqf(__builtin_fmaf(ssr, 1.0f / 64.0f, 1e-5f));

        // softmax over 32 out-chs; max-pass skipped (|logit*rs| small, fp32-safe);
        // log2e folded into rs so each exp is a single v_exp_f32 after one mul.
        const float rs2 = rs * 1.44269504f;
        float e0[4], e1[4];
        float lsum = 0.f;
#pragma unroll
        for (int r = 0; r < 4; ++r) {
            e0[r] = __builtin_amdgcn_exp2f(lg0[r] * rs2);
            e1[r] = __builtin_amdgcn_exp2f(lg1[r] * rs2);
            lsum += e0[r] + e1[r];
        }
        lsum += __shfl_xor(lsum, 16, 64);
        lsum += __shfl_xor(lsum, 32, 64);
        const float inv = fast_rcp(lsum);

        const long orow = rowBase + (long)tile * 16 + c;
        *(float4*)(out + orow * 32 + 4 * q) =
            make_float4(e0[0] * inv, e0[1] * inv, e0[2] * inv, e0[3] * inv);
        *(float4*)(out + orow * 32 + 16 + 4 * q) =
            make_float4(e1[0] * inv, e1[1] * inv, e1[2] * inv, e1[3] * inv);

        xa = na; xb = nb; xct = nc2;
    }
}

extern "C" void kernel_launch(void* const* d_in, const int* in_sizes, int n_in,
                              void* d_out, int out_size, void* d_ws, size_t ws_size,
                              hipStream_t stream) {
    const float* x          = (const float*)d_in[0];
    const float* f_out_w    = (const float*)d_in[1];
    const float* f_out_b    = (const float*)d_in[2];
    const float* in_proj_w  = (const float*)d_in[3];
    const float* conv_w     = (const float*)d_in[4];
    const float* conv_b     = (const float*)d_in[5];
    const float* dt_bias    = (const float*)d_in[6];
    // d_in[7] = A_log — unused by the reference
    const float* D_skip     = (const float*)d_in[8];
    const float* norm_w     = (const float*)d_in[9];
    const float* out_proj_w = (const float*)d_in[10];
    float* out = (float*)d_out;

    const int n = in_sizes[0] / IN_DIM;                 // 524288
    const int tiles_per_wave = n / (BLOCKS * 4 * 16);   // 4

    hipLaunchKernelGGL(prep_kernel, dim3(24), dim3(64), 0, stream,
                       f_out_w, f_out_b, in_proj_w, conv_w, conv_b, dt_bias,
                       norm_w, out_proj_w, d_ws);
    hipLaunchKernelGGL(mamba_mfma_kernel, dim3(BLOCKS), dim3(256), 0, stream,
                       x, D_skip, d_ws, out, tiles_per_wave);
}

// Round 11
// 163.775 us; speedup vs baseline: 1.1271x; 1.1271x over previous
//
#include <hip/hip_runtime.h>
#include <math.h>

typedef _Float16 half8 __attribute__((ext_vector_type(8)));
typedef __fp16 fp16x2 __attribute__((ext_vector_type(2)));
typedef float floatx4 __attribute__((ext_vector_type(4)));
typedef float floatx2 __attribute__((ext_vector_type(2)));

constexpr int IN_DIM = 36;
constexpr int BLOCKS = 2048;
// R16 channel map (prep-side remaps; zxbcdt source channels):
//   z-tile u (fid 2u):   tile-row c = z ch  8*(c>>2) + 4*(u&1) + (c&3) + 32*(u>>1)
//   xh-tile u (fid 8+2u): same + 64
//   => after GEMM1, lane (c,q) holds y chs {8q..8q+7} (t=0,1) and
//      {32+8q..+7} (t=2,3)  ==  GEMM2 By0/By1 IN REGISTER (no LDS hop).
//      Head of every ch in tile t for lane q: q + 4*(t>=2).
//   tile 8 (B/C interleave, R15): row c = ((c&1)?136:128) + 2*(c>>2) + ((c>>1)&1)
//   tile 9 (dt):          row c = 144 + (c>>2) + 4*((c&3)>>1)
//      => lane q: acc9[0] = dt head q, acc9[2] = dt head q+4.

__device__ __forceinline__ float fast_rcp(float v) { return __builtin_amdgcn_rcpf(v); }
__device__ __forceinline__ float softplus_f(float v) {
    return fmaxf(v, 0.0f) + __logf(1.0f + __expf(-fabsf(v)));
}
__device__ __forceinline__ float pk2f(float a, float b) {
    fp16x2 p = __builtin_amdgcn_cvt_pkrtz(a, b);   // v_cvt_pkrtz_f16_f32
    return __builtin_bit_cast(float, p);
}

// ---- prep: 24 fp16 A-operand fragments into d_ws (one block per fragment) ----
// fid 0..19: GEMM1 A = Wc^T (Wc[k][ch] = sum_m f_out_w[m][k]*in_proj_w[ch][m],
//   conv_w folded for ch in [64,144)). Ghost k=36 carries the fully-fused bias.
// fid 20..23: GEMM2 A = out_proj_w[m][k] * norm_w[k] (norm fold).
extern "C" __global__ void __launch_bounds__(64)
prep_kernel(const float* __restrict__ f_out_w, const float* __restrict__ f_out_b,
            const float* __restrict__ in_proj_w, const float* __restrict__ conv_w,
            const float* __restrict__ conv_b, const float* __restrict__ dt_bias,
            const float* __restrict__ norm_w, const float* __restrict__ out_proj_w,
            void* __restrict__ ws) {
    const int fid = blockIdx.x;
    const int L = threadIdx.x;
    const int c = L & 15, q = L >> 4;
    unsigned short* fr = (unsigned short*)ws;
    for (int j = 0; j < 8; ++j) {
        float val = 0.f;
        if (fid < 20) {
            const int t = fid >> 1, ks = fid & 1;
            int m;
            if (t < 8) {                            // z (t<4) / xh (t>=4) remap
                const int u = t & 3;
                m = ((t < 4) ? 0 : 64) +
                    8 * (c >> 2) + 4 * (u & 1) + (c & 3) + 32 * (u >> 1);
            } else if (t == 8) {                    // B/C interleave remap (R15)
                m = ((c & 1) ? 136 : 128) + 2 * (c >> 2) + ((c >> 1) & 1);
            } else {                                // dt: heads {q, q+4} per lane
                m = 144 + (c >> 2) + 4 * ((c & 3) >> 1);
            }
            const int k = ks * 32 + q * 8 + j;      // feature
            if (m < 152) {
                if (k < IN_DIM) {
                    float acc = 0.f;
                    for (int mm = 0; mm < 32; ++mm)
                        acc += f_out_w[mm * IN_DIM + k] * in_proj_w[m * 32 + mm];
                    if (m >= 64 && m < 144) acc *= conv_w[(m - 64) * 2 + 1];
                    val = acc;
                } else if (k == IN_DIM) {           // ghost-feature bias slot
                    float acc = 0.f;
                    for (int mm = 0; mm < 32; ++mm)
                        acc += f_out_b[mm] * in_proj_w[m * 32 + mm];
                    if (m >= 64 && m < 144)      val = acc * conv_w[(m - 64) * 2 + 1] + conv_b[m - 64];
                    else if (m >= 144)           val = acc + dt_bias[m - 144];
                    else                         val = acc;
                }
            }
        } else {
            const int mt = (fid - 20) >> 1, ks = (fid - 20) & 1;
            const int m = mt * 16 + c;              // out channel (<32)
            const int k = ks * 32 + q * 8 + j;      // y channel (<64)
            val = out_proj_w[m * 64 + k] * norm_w[k];
        }
        _Float16 h = (_Float16)val;
        fr[fid * 512 + L * 8 + j] = __builtin_bit_cast(unsigned short, h);
    }
}

// ---- main: transposed GEMMs; lane (c,q) owns row c of its 16-row tile ----
// R18 = R16 body at (256,3) ((256,4) closed for good: R8/R10/R14/R17 all
// spilled) + front-phase software pipeline: tile t+1's FRONT (pack Bx,
// MFMA 8/9, bc shuffles, softplus -> scl) runs textually before tile t's
// TAIL (z/xh MFMAs, exp block, GEMM2, softmax, store). Unlike R12 (which
// carried the 40-reg acc blob across the tail and spilled), the front's
// carried state is only BxN (8) + sclN (2) = +10 regs. The front's serial
// latency chain (2 MFMA -> 2 ds_bpermute -> softplus, ~250cy) now overlaps
// the tail's MFMA + transcendental work on disjoint pipes instead of
// serializing ahead of it.
// Spill tripwire: FETCH ~37MB / WRITE ~65.5MB must not move.
extern "C" __global__ void __launch_bounds__(256, 3)
mamba_mfma_kernel(const float* __restrict__ x,
                  const float* __restrict__ D_skip,
                  const void* __restrict__ ws,
                  float* __restrict__ out,
                  int tiles_per_wave) {
    __shared__ float4 ldsW[1536];                  // 24 KiB: 24 A-fragments, 16B-aligned
    const int lane = threadIdx.x & 63;
    const int wv   = threadIdx.x >> 6;
    const int c = lane & 15, q = lane >> 4;

    // cooperative stage of all 24 fragments: 24576 B / 256 thr = 6 float4 each
    {
        const float4* src = (const float4*)ws;
#pragma unroll
        for (int i = 0; i < 6; ++i)
            ldsW[threadIdx.x + 256 * i] = src[threadIdx.x + 256 * i];
    }

    // D_skip for this lane's two heads (q and q+4)
    const float dsk0 = D_skip[q];
    const float dsk1 = D_skip[q + 4];

    const long rowBase = (long)(blockIdx.x * 4 + wv) * tiles_per_wave * 16;
    const float* xrow = x + (rowBase + c) * (long)IN_DIM;
    const float4 zf4 = make_float4(0.f, 0.f, 0.f, 0.f);
    const char* Wb = (const char*)ldsW;

    auto packBx = [&](const float4 fxa, const float4 fxb, const float4 fxct,
                      half8& B0, half8& B1) {
        float4 t0, t1;
        t0.x = pk2f(fxa.x, fxa.y);
        t0.y = pk2f(fxa.z, fxa.w);
        t0.z = pk2f(fxb.x, fxb.y);
        t0.w = pk2f(fxb.z, fxb.w);
        t1.x = pk2f(fxct.x, fxct.y);                // fxct already 0 for q!=0
        t1.y = pk2f(fxct.z, fxct.w);
        t1.z = (q == 0) ? pk2f(1.0f, 0.0f) : 0.0f;  // ghost feature -> bias
        t1.w = 0.0f;
        B0 = __builtin_bit_cast(half8, t0);
        B1 = __builtin_bit_cast(half8, t1);
    };

    // FRONT: tiles 8/9 MFMAs + lane-local bc + per-head scales (R15/R16 maps)
    auto front = [&](const half8 B0, const half8 B1, float& s0, float& s1) {
        const half8 c80 = *(const half8*)(Wb + (size_t)(16 * 64 + lane) * 16);
        const half8 c81 = *(const half8*)(Wb + (size_t)(17 * 64 + lane) * 16);
        const half8 c90 = *(const half8*)(Wb + (size_t)(18 * 64 + lane) * 16);
        const half8 c91 = *(const half8*)(Wb + (size_t)(19 * 64 + lane) * 16);
        floatx4 z4 = {0.f, 0.f, 0.f, 0.f};
        floatx4 a8 = __builtin_amdgcn_mfma_f32_16x16x32_f16(c80, B0, z4, 0, 0, 0);
        a8 = __builtin_amdgcn_mfma_f32_16x16x32_f16(c81, B1, a8, 0, 0, 0);
        floatx4 a9 = __builtin_amdgcn_mfma_f32_16x16x32_f16(c90, B0, z4, 0, 0, 0);
        a9 = __builtin_amdgcn_mfma_f32_16x16x32_f16(c91, B1, a9, 0, 0, 0);

        // bc: in-lane silu(B[s])*silu(C[s]) pairs, xor16 + xor32 sum
        const float b0 = a8[0], c0 = a8[1], b1 = a8[2], c1 = a8[3];
        const float d0 = (1.0f + __expf(-b0)) * (1.0f + __expf(-c0));
        const float d1 = (1.0f + __expf(-b1)) * (1.0f + __expf(-c1));
        float part = b0 * c0 * fast_rcp(d0) + b1 * c1 * fast_rcp(d1);
        const float h1 = part + __shfl_xor(part, 16, 64);
        const float bc = h1 + __shfl_xor(h1, 32, 64);

        s0 = __builtin_fmaf(softplus_f(a9[0]), bc, dsk0);
        s1 = __builtin_fmaf(softplus_f(a9[2]), bc, dsk1);
    };

    // -------- prologue --------
    half8 Bx0, Bx1;               // current tile's packed B-operand
    float sclH0, sclH1;           // current tile's head scales
    float4 xa, xb, xct;           // x of NEXT tile (1-deep prefetch)
    {
        float4 ta, tb, tc;
        ta = *(const float4*)(xrow + q * 8);
        tb = *(const float4*)(xrow + q * 8 + 4);
        tc = (q == 0) ? *(const float4*)(xrow + 32) : zf4;
        const int p1 = (tiles_per_wave > 1) ? 1 : 0;
        xa = *(const float4*)(xrow + (size_t)p1 * 16 * IN_DIM + q * 8);
        xb = *(const float4*)(xrow + (size_t)p1 * 16 * IN_DIM + q * 8 + 4);
        xct = (q == 0) ? *(const float4*)(xrow + (size_t)p1 * 16 * IN_DIM + 32) : zf4;
        __syncthreads();                           // weights resident in LDS
        packBx(ta, tb, tc, Bx0, Bx1);
        front(Bx0, Bx1, sclH0, sclH1);
    }

#pragma unroll 1
    for (int tile = 0; tile < tiles_per_wave; ++tile) {
        // ---- next tile's FRONT first: its MFMA+shuffle+softplus chain
        // interleaves with this tile's tail below (disjoint pipes) ----
        half8 BxN0 = Bx0, BxN1 = Bx1;
        float sclN0 = sclH0, sclN1 = sclH1;
        if (tile + 1 < tiles_per_wave) {
            packBx(xa, xb, xct, BxN0, BxN1);
            const int pt = (tile + 2 < tiles_per_wave) ? tile + 2 : tiles_per_wave - 1;
            const float* p = xrow + (size_t)pt * 16 * IN_DIM;
            xa = *(const float4*)(p + q * 8);
            xb = *(const float4*)(p + q * 8 + 4);
            xct = (q == 0) ? *(const float4*)(p + 32) : zf4;
            front(BxN0, BxN1, sclN0, sclN1);
        }

        // ---- current tile's TAIL ----
        // z/xh pairs: 4 MFMAs per t, consumed immediately into By (R16 map)
        float4 by0f, by1f;
        float ssum = 0.f;
#pragma unroll
        for (int t = 0; t < 4; ++t) {
            const half8 cz0 = *(const half8*)(Wb + (size_t)((t * 2 + 0) * 64 + lane) * 16);
            const half8 cz1 = *(const half8*)(Wb + (size_t)((t * 2 + 1) * 64 + lane) * 16);
            const half8 cx0 = *(const half8*)(Wb + (size_t)(((t + 4) * 2 + 0) * 64 + lane) * 16);
            const half8 cx1 = *(const half8*)(Wb + (size_t)(((t + 4) * 2 + 1) * 64 + lane) * 16);
            floatx4 z4 = {0.f, 0.f, 0.f, 0.f};
            floatx4 az = __builtin_amdgcn_mfma_f32_16x16x32_f16(cz0, Bx0, z4, 0, 0, 0);
            az = __builtin_amdgcn_mfma_f32_16x16x32_f16(cz1, Bx1, az, 0, 0, 0);
            floatx4 ax = __builtin_amdgcn_mfma_f32_16x16x32_f16(cx0, Bx0, z4, 0, 0, 0);
            ax = __builtin_amdgcn_mfma_f32_16x16x32_f16(cx1, Bx1, ax, 0, 0, 0);

            const float scl = (t < 2) ? sclH0 : sclH1;
            float v[4];
#pragma unroll
            for (int r = 0; r < 4; ++r) {
                const float zr = az[r], xh = ax[r];
                const float den = (1.0f + __expf(-zr)) * (1.0f + __expf(-xh));
                v[r] = zr * xh * scl * fast_rcp(den);
                ssum = __builtin_fmaf(v[r], v[r], ssum);
            }
            const float plo = pk2f(v[0], v[1]);
            const float phi = pk2f(v[2], v[3]);
            if (t == 0)      { by0f.x = plo; by0f.y = phi; }
            else if (t == 1) { by0f.z = plo; by0f.w = phi; }
            else if (t == 2) { by1f.x = plo; by1f.y = phi; }
            else             { by1f.z = plo; by1f.w = phi; }
        }
        const half8 By0 = __builtin_bit_cast(half8, by0f);
        const half8 By1 = __builtin_bit_cast(half8, by1f);

        // GEMM2 (weights) — independent of the ssum chain, overlaps it
        const half8 A300 = *(const half8*)(Wb + (size_t)(20 * 64 + lane) * 16);
        const half8 A301 = *(const half8*)(Wb + (size_t)(21 * 64 + lane) * 16);
        const half8 A310 = *(const half8*)(Wb + (size_t)(22 * 64 + lane) * 16);
        const half8 A311 = *(const half8*)(Wb + (size_t)(23 * 64 + lane) * 16);

        floatx4 z4 = {0.f, 0.f, 0.f, 0.f};
        floatx4 lg0 = __builtin_amdgcn_mfma_f32_16x16x32_f16(A300, By0, z4, 0, 0, 0);
        lg0 = __builtin_amdgcn_mfma_f32_16x16x32_f16(A301, By1, lg0, 0, 0, 0);
        floatx4 lg1 = __builtin_amdgcn_mfma_f32_16x16x32_f16(A310, By0, z4, 0, 0, 0);
        lg1 = __builtin_amdgcn_mfma_f32_16x16x32_f16(A311, By1, lg1, 0, 0, 0);

        float ssr = ssum + __shfl_xor(ssum, 16, 64);
        ssr += __shfl_xor(ssr, 32, 64);
        const float rs = __builtin_amdgcn_rsqf(__builtin_fmaf(ssr, 1.0f / 64.0f, 1e-5f));

        // softmax over 32 out-chs; max-pass skipped (|logit*rs| small, fp32-safe)
        const float rs2 = rs * 1.44269504f;
        float e0[4], e1[4];
        float lsum = 0.f;
#pragma unroll
        for (int r = 0; r < 4; ++r) {
            e0[r] = __builtin_amdgcn_exp2f(lg0[r] * rs2);
            e1[r] = __builtin_amdgcn_exp2f(lg1[r] * rs2);
            lsum += e0[r] + e1[r];
        }
        lsum += __shfl_xor(lsum, 16, 64);
        lsum += __shfl_xor(lsum, 32, 64);
        const float inv = fast_rcp(lsum);

        const long orow = rowBase + (long)tile * 16 + c;
        *(float4*)(out + orow * 32 + 4 * q) =
            make_float4(e0[0] * inv, e0[1] * inv, e0[2] * inv, e0[3] * inv);
        *(float4*)(out + orow * 32 + 16 + 4 * q) =
            make_float4(e1[0] * inv, e1[1] * inv, e1[2] * inv, e1[3] * inv);

        // rotate pipeline state
        Bx0 = BxN0; Bx1 = BxN1; sclH0 = sclN0; sclH1 = sclN1;
    }
}

extern "C" void kernel_launch(void* const* d_in, const int* in_sizes, int n_in,
                              void* d_out, int out_size, void* d_ws, size_t ws_size,
                              hipStream_t stream) {
    const float* x          = (const float*)d_in[0];
    const float* f_out_w    = (const float*)d_in[1];
    const float* f_out_b    = (const float*)d_in[2];
    const float* in_proj_w  = (const float*)d_in[3];
    const float* conv_w     = (const float*)d_in[4];
    const float* conv_b     = (const float*)d_in[5];
    const float* dt_bias    = (const float*)d_in[6];
    // d_in[7] = A_log — unused by the reference
    const float* D_skip     = (const float*)d_in[8];
    const float* norm_w     = (const float*)d_in[9];
    const float* out_proj_w = (const float*)d_in[10];
    float* out = (float*)d_out;

    const int n = in_sizes[0] / IN_DIM;                 // 524288
    const int tiles_per_wave = n / (BLOCKS * 4 * 16);   // 4

    hipLaunchKernelGGL(prep_kernel, dim3(24), dim3(64), 0, stream,
                       f_out_w, f_out_b, in_proj_w, conv_w, conv_b, dt_bias,
                       norm_w, out_proj_w, d_ws);
    hipLaunchKernelGGL(mamba_mfma_kernel, dim3(BLOCKS), dim3(256), 0, stream,
                       x, D_skip, d_ws, out, tiles_per_wave);
}

// Round 12
// 161.840 us; speedup vs baseline: 1.1406x; 1.0120x over previous
//
#include <hip/hip_runtime.h>
#include <math.h>

typedef _Float16 half8 __attribute__((ext_vector_type(8)));
typedef __fp16 fp16x2 __attribute__((ext_vector_type(2)));
typedef float floatx4 __attribute__((ext_vector_type(4)));
typedef float floatx2 __attribute__((ext_vector_type(2)));

constexpr int IN_DIM = 36;
constexpr int BLOCKS = 8192;   // R19: 1 tile per wave -> short blocks, dispatcher
                               // backfill staggers co-resident waves (convoy fix)
// R16 channel map (prep-side remaps; zxbcdt source channels):
//   z-tile u (fid 2u):   tile-row c = z ch  8*(c>>2) + 4*(u&1) + (c&3) + 32*(u>>1)
//   xh-tile u (fid 8+2u): same + 64
//   => after GEMM1, lane (c,q) holds y chs {8q..8q+7} (t=0,1) and
//      {32+8q..+7} (t=2,3)  ==  GEMM2 By0/By1 IN REGISTER (no LDS hop).
//      Head of every ch in tile t for lane q: q + 4*(t>=2).
//   tile 8 (B/C interleave, R15): row c = ((c&1)?136:128) + 2*(c>>2) + ((c>>1)&1)
//   tile 9 (dt):          row c = 144 + (c>>2) + 4*((c&3)>>1)
//      => lane q: acc9[0] = dt head q, acc9[2] = dt head q+4.

__device__ __forceinline__ float fast_rcp(float v) { return __builtin_amdgcn_rcpf(v); }
__device__ __forceinline__ float softplus_f(float v) {
    return fmaxf(v, 0.0f) + __logf(1.0f + __expf(-fabsf(v)));
}
__device__ __forceinline__ float pk2f(float a, float b) {
    fp16x2 p = __builtin_amdgcn_cvt_pkrtz(a, b);   // v_cvt_pkrtz_f16_f32
    return __builtin_bit_cast(float, p);
}

// ---- prep: 24 fp16 A-operand fragments into d_ws (one block per fragment) ----
// fid 0..19: GEMM1 A = Wc^T (Wc[k][ch] = sum_m f_out_w[m][k]*in_proj_w[ch][m],
//   conv_w folded for ch in [64,144)). Ghost k=36 carries the fully-fused bias.
// fid 20..23: GEMM2 A = out_proj_w[m][k] * norm_w[k] (norm fold).
extern "C" __global__ void __launch_bounds__(64)
prep_kernel(const float* __restrict__ f_out_w, const float* __restrict__ f_out_b,
            const float* __restrict__ in_proj_w, const float* __restrict__ conv_w,
            const float* __restrict__ conv_b, const float* __restrict__ dt_bias,
            const float* __restrict__ norm_w, const float* __restrict__ out_proj_w,
            void* __restrict__ ws) {
    const int fid = blockIdx.x;
    const int L = threadIdx.x;
    const int c = L & 15, q = L >> 4;
    unsigned short* fr = (unsigned short*)ws;
    for (int j = 0; j < 8; ++j) {
        float val = 0.f;
        if (fid < 20) {
            const int t = fid >> 1, ks = fid & 1;
            int m;
            if (t < 8) {                            // z (t<4) / xh (t>=4) remap
                const int u = t & 3;
                m = ((t < 4) ? 0 : 64) +
                    8 * (c >> 2) + 4 * (u & 1) + (c & 3) + 32 * (u >> 1);
            } else if (t == 8) {                    // B/C interleave remap (R15)
                m = ((c & 1) ? 136 : 128) + 2 * (c >> 2) + ((c >> 1) & 1);
            } else {                                // dt: heads {q, q+4} per lane
                m = 144 + (c >> 2) + 4 * ((c & 3) >> 1);
            }
            const int k = ks * 32 + q * 8 + j;      // feature
            if (m < 152) {
                if (k < IN_DIM) {
                    float acc = 0.f;
                    for (int mm = 0; mm < 32; ++mm)
                        acc += f_out_w[mm * IN_DIM + k] * in_proj_w[m * 32 + mm];
                    if (m >= 64 && m < 144) acc *= conv_w[(m - 64) * 2 + 1];
                    val = acc;
                } else if (k == IN_DIM) {           // ghost-feature bias slot
                    float acc = 0.f;
                    for (int mm = 0; mm < 32; ++mm)
                        acc += f_out_b[mm] * in_proj_w[m * 32 + mm];
                    if (m >= 64 && m < 144)      val = acc * conv_w[(m - 64) * 2 + 1] + conv_b[m - 64];
                    else if (m >= 144)           val = acc + dt_bias[m - 144];
                    else                         val = acc;
                }
            }
        } else {
            const int mt = (fid - 20) >> 1, ks = (fid - 20) & 1;
            const int m = mt * 16 + c;              // out channel (<32)
            const int k = ks * 32 + q * 8 + j;      // y channel (<64)
            val = out_proj_w[m * 64 + k] * norm_w[k];
        }
        _Float16 h = (_Float16)val;
        fr[fid * 512 + L * 8 + j] = __builtin_bit_cast(unsigned short, h);
    }
}

// ---- main: transposed GEMMs; lane (c,q) owns row c of its 16-row tile ----
// R19 = R16 body exactly (best clean body: y-in-register GEMM2, lane-local
// bc/scale, 0 bank conflicts, LDS 24.5KB, (256,3); R18's front-pipeline cost
// +4us and is reverted) with ONE change: BLOCKS 2048 -> 8192, tiles_per_wave
// 4 -> 1. Theory: five different bodies all plateau at 45-50us because
// co-resident waves are PHASE-LOCKED — identical blocks, launched in the
// same round, execute the same instruction stream in lockstep, so their
// stall windows coincide and 3 waves/SIMD hide latency no better than 1.
// Short blocks let the dispatcher backfill at ragged completion times,
// staggering wave phases naturally. Cost: weight staging amortized over 1
// tile not 4 (~5-8%, L2-resident).
extern "C" __global__ void __launch_bounds__(256, 3)
mamba_mfma_kernel(const float* __restrict__ x,
                  const float* __restrict__ D_skip,
                  const void* __restrict__ ws,
                  float* __restrict__ out,
                  int tiles_per_wave) {
    __shared__ float4 ldsW[1536];                  // 24 KiB: 24 A-fragments, 16B-aligned
    const int lane = threadIdx.x & 63;
    const int wv   = threadIdx.x >> 6;
    const int c = lane & 15, q = lane >> 4;

    // cooperative stage of all 24 fragments: 24576 B / 256 thr = 6 float4 each
    {
        const float4* src = (const float4*)ws;
#pragma unroll
        for (int i = 0; i < 6; ++i)
            ldsW[threadIdx.x + 256 * i] = src[threadIdx.x + 256 * i];
    }

    // D_skip for this lane's two heads (q and q+4)
    const float dsk0 = D_skip[q];
    const float dsk1 = D_skip[q + 4];

    const long rowBase = (long)(blockIdx.x * 4 + wv) * tiles_per_wave * 16;
    const float* xrow = x + (rowBase + c) * (long)IN_DIM;

    float4 xa, xb, xct;
    {
        const float* p = xrow + q * 8;
        xa = *(const float4*)p;
        xb = *(const float4*)(p + 4);
        xct = (q == 0) ? *(const float4*)(xrow + 32) : make_float4(0.f, 0.f, 0.f, 0.f);
    }

    __syncthreads();                               // weights resident in LDS
    const char* Wb = (const char*)ldsW;

#pragma unroll 1
    for (int tile = 0; tile < tiles_per_wave; ++tile) {
        float4 na = xa, nb = xb, nc2 = xct;
        if (tile + 1 < tiles_per_wave) {
            const float* p = xrow + (size_t)(tile + 1) * 16 * IN_DIM + q * 8;
            na = *(const float4*)p;
            nb = *(const float4*)(p + 4);
            if (q == 0) nc2 = *(const float4*)(xrow + (size_t)(tile + 1) * 16 * IN_DIM + 32);
        }

        // B-operand from x, packed with v_cvt_pkrtz (2 floats/op); bit_cast keeps
        // everything in registers (unions here caused scratch spills in R6).
        float4 t0, t1;
        t0.x = pk2f(xa.x, xa.y);
        t0.y = pk2f(xa.z, xa.w);
        t0.z = pk2f(xb.x, xb.y);
        t0.w = pk2f(xb.z, xb.w);
        t1.x = pk2f(xct.x, xct.y);                  // xct already 0 for q!=0
        t1.y = pk2f(xct.z, xct.w);
        t1.z = (q == 0) ? pk2f(1.0f, 0.0f) : 0.0f;  // ghost feature -> bias
        t1.w = 0.0f;
        const half8 Bx0 = __builtin_bit_cast(half8, t0);
        const half8 Bx1 = __builtin_bit_cast(half8, t1);

        // ---- tiles 8 (B/C interleaved) and 9 (dt remapped) first ----
        floatx4 acc8, acc9;
        {
            const half8 c80 = *(const half8*)(Wb + (size_t)(16 * 64 + lane) * 16);
            const half8 c81 = *(const half8*)(Wb + (size_t)(17 * 64 + lane) * 16);
            const half8 c90 = *(const half8*)(Wb + (size_t)(18 * 64 + lane) * 16);
            const half8 c91 = *(const half8*)(Wb + (size_t)(19 * 64 + lane) * 16);
            floatx4 z4 = {0.f, 0.f, 0.f, 0.f};
            acc8 = __builtin_amdgcn_mfma_f32_16x16x32_f16(c80, Bx0, z4, 0, 0, 0);
            acc8 = __builtin_amdgcn_mfma_f32_16x16x32_f16(c81, Bx1, acc8, 0, 0, 0);
            acc9 = __builtin_amdgcn_mfma_f32_16x16x32_f16(c90, Bx0, z4, 0, 0, 0);
            acc9 = __builtin_amdgcn_mfma_f32_16x16x32_f16(c91, Bx1, acc9, 0, 0, 0);
        }

        // bc: in-lane silu(B[s])*silu(C[s]) pairs (s = 2q + {0,1}), then
        // xor16 + xor32 sum over the 4 q-lanes -> bc in ALL lanes. 2 shuffles.
        float part;
        {
            const float b0 = acc8[0], c0 = acc8[1], b1 = acc8[2], c1 = acc8[3];
            const float d0 = (1.0f + __expf(-b0)) * (1.0f + __expf(-c0));
            const float d1 = (1.0f + __expf(-b1)) * (1.0f + __expf(-c1));
            part = b0 * c0 * fast_rcp(d0) + b1 * c1 * fast_rcp(d1);
        }
        const float h1 = part + __shfl_xor(part, 16, 64);
        const float bc = h1 + __shfl_xor(h1, 32, 64);

        // per-head scale, lane-local: acc9[0] = dt head q, acc9[2] = head q+4
        const float sclH0 = __builtin_fmaf(softplus_f(acc9[0]), bc, dsk0);
        const float sclH1 = __builtin_fmaf(softplus_f(acc9[2]), bc, dsk1);

        // ---- z/xh pairs: 4 MFMAs per t, consumed immediately into By ----
        // tile t supplies y chs {8q + 4*(t&1) + r + 32*(t>>1)} (head q+4*(t>>1))
        // -> packed pk2f pairs land DIRECTLY in By0 (t=0,1) / By1 (t=2,3).
        float4 by0f, by1f;
        float ssum = 0.f;
#pragma unroll
        for (int t = 0; t < 4; ++t) {
            const half8 cz0 = *(const half8*)(Wb + (size_t)((t * 2 + 0) * 64 + lane) * 16);
            const half8 cz1 = *(const half8*)(Wb + (size_t)((t * 2 + 1) * 64 + lane) * 16);
            const half8 cx0 = *(const half8*)(Wb + (size_t)(((t + 4) * 2 + 0) * 64 + lane) * 16);
            const half8 cx1 = *(const half8*)(Wb + (size_t)(((t + 4) * 2 + 1) * 64 + lane) * 16);
            floatx4 z4 = {0.f, 0.f, 0.f, 0.f};
            floatx4 az = __builtin_amdgcn_mfma_f32_16x16x32_f16(cz0, Bx0, z4, 0, 0, 0);
            az = __builtin_amdgcn_mfma_f32_16x16x32_f16(cz1, Bx1, az, 0, 0, 0);
            floatx4 ax = __builtin_amdgcn_mfma_f32_16x16x32_f16(cx0, Bx0, z4, 0, 0, 0);
            ax = __builtin_amdgcn_mfma_f32_16x16x32_f16(cx1, Bx1, ax, 0, 0, 0);

            const float scl = (t < 2) ? sclH0 : sclH1;
            float v[4];
#pragma unroll
            for (int r = 0; r < 4; ++r) {
                const float zr = az[r], xh = ax[r];
                const float den = (1.0f + __expf(-zr)) * (1.0f + __expf(-xh));
                v[r] = zr * xh * scl * fast_rcp(den);
                ssum = __builtin_fmaf(v[r], v[r], ssum);
            }
            const float plo = pk2f(v[0], v[1]);
            const float phi = pk2f(v[2], v[3]);
            if (t == 0)      { by0f.x = plo; by0f.y = phi; }
            else if (t == 1) { by0f.z = plo; by0f.w = phi; }
            else if (t == 2) { by1f.x = plo; by1f.y = phi; }
            else             { by1f.z = plo; by1f.w = phi; }
        }
        const half8 By0 = __builtin_bit_cast(half8, by0f);
        const half8 By1 = __builtin_bit_cast(half8, by1f);

        // GEMM2 A-fragments (weights) + MFMAs — independent of the ssum chain,
        // so they overlap the reduction shuffles below.
        const half8 A300 = *(const half8*)(Wb + (size_t)(20 * 64 + lane) * 16);
        const half8 A301 = *(const half8*)(Wb + (size_t)(21 * 64 + lane) * 16);
        const half8 A310 = *(const half8*)(Wb + (size_t)(22 * 64 + lane) * 16);
        const half8 A311 = *(const half8*)(Wb + (size_t)(23 * 64 + lane) * 16);

        floatx4 z4 = {0.f, 0.f, 0.f, 0.f};
        floatx4 lg0 = __builtin_amdgcn_mfma_f32_16x16x32_f16(A300, By0, z4, 0, 0, 0);
        lg0 = __builtin_amdgcn_mfma_f32_16x16x32_f16(A301, By1, lg0, 0, 0, 0);
        floatx4 lg1 = __builtin_amdgcn_mfma_f32_16x16x32_f16(A310, By0, z4, 0, 0, 0);
        lg1 = __builtin_amdgcn_mfma_f32_16x16x32_f16(A311, By1, lg1, 0, 0, 0);

        float ssr = ssum + __shfl_xor(ssum, 16, 64);
        ssr += __shfl_xor(ssr, 32, 64);
        const float rs = __builtin_amdgcn_rsqf(__builtin_fmaf(ssr, 1.0f / 64.0f, 1e-5f));

        // softmax over 32 out-chs; max-pass skipped (|logit*rs| small, fp32-safe);
        // log2e folded into rs so each exp is a single v_exp_f32 after one mul.
        const float rs2 = rs * 1.44269504f;
        float e0[4], e1[4];
        float lsum = 0.f;
#pragma unroll
        for (int r = 0; r < 4; ++r) {
            e0[r] = __builtin_amdgcn_exp2f(lg0[r] * rs2);
            e1[r] = __builtin_amdgcn_exp2f(lg1[r] * rs2);
            lsum += e0[r] + e1[r];
        }
        lsum += __shfl_xor(lsum, 16, 64);
        lsum += __shfl_xor(lsum, 32, 64);
        const float inv = fast_rcp(lsum);

        const long orow = rowBase + (long)tile * 16 + c;
        *(float4*)(out + orow * 32 + 4 * q) =
            make_float4(e0[0] * inv, e0[1] * inv, e0[2] * inv, e0[3] * inv);
        *(float4*)(out + orow * 32 + 16 + 4 * q) =
            make_float4(e1[0] * inv, e1[1] * inv, e1[2] * inv, e1[3] * inv);

        xa = na; xb = nb; xct = nc2;
    }
}

extern "C" void kernel_launch(void* const* d_in, const int* in_sizes, int n_in,
                              void* d_out, int out_size, void* d_ws, size_t ws_size,
                              hipStream_t stream) {
    const float* x          = (const float*)d_in[0];
    const float* f_out_w    = (const float*)d_in[1];
    const float* f_out_b    = (const float*)d_in[2];
    const float* in_proj_w  = (const float*)d_in[3];
    const float* conv_w     = (const float*)d_in[4];
    const float* conv_b     = (const float*)d_in[5];
    const float* dt_bias    = (const float*)d_in[6];
    // d_in[7] = A_log — unused by the reference
    const float* D_skip     = (const float*)d_in[8];
    const float* norm_w     = (const float*)d_in[9];
    const float* out_proj_w = (const float*)d_in[10];
    float* out = (float*)d_out;

    const int n = in_sizes[0] / IN_DIM;                 // 524288
    const int tiles_per_wave = n / (BLOCKS * 4 * 16);   // 1 at BLOCKS=8192

    hipLaunchKernelGGL(prep_kernel, dim3(24), dim3(64), 0, stream,
                       f_out_w, f_out_b, in_proj_w, conv_w, conv_b, dt_bias,
                       norm_w, out_proj_w, d_ws);
    hipLaunchKernelGGL(mamba_mfma_kernel, dim3(BLOCKS), dim3(256), 0, stream,
                       x, D_skip, d_ws, out, tiles_per_wave);
}

// Round 13
// 155.650 us; speedup vs baseline: 1.1860x; 1.0398x over previous
//
#include <hip/hip_runtime.h>
#include <math.h>

typedef _Float16 half8 __attribute__((ext_vector_type(8)));
typedef __fp16 fp16x2 __attribute__((ext_vector_type(2)));
typedef float floatx4 __attribute__((ext_vector_type(4)));
typedef float floatx2 __attribute__((ext_vector_type(2)));

constexpr int IN_DIM = 36;
constexpr int BLOCKS = 2048;   // R20: revert to R16's grid (R19's 8192 lost the
                               // 4-tile staging amortization; convoy theory null)
// R16 channel map (prep-side remaps; zxbcdt source channels):
//   z-tile u (fid 2u):   tile-row c = z ch  8*(c>>2) + 4*(u&1) + (c&3) + 32*(u>>1)
//   xh-tile u (fid 8+2u): same + 64
//   => after GEMM1, lane (c,q) holds y chs {8q..8q+7} (t=0,1) and
//      {32+8q..+7} (t=2,3)  ==  GEMM2 By0/By1 IN REGISTER (no LDS hop).
//      Head of every ch in tile t for lane q: q + 4*(t>=2).
//   tile 8 (B/C interleave, R15): row c = ((c&1)?136:128) + 2*(c>>2) + ((c>>1)&1)
//   tile 9 (dt):          row c = 144 + (c>>2) + 4*((c&3)>>1)
//      => lane q: acc9[0] = dt head q, acc9[2] = dt head q+4.

__device__ __forceinline__ float fast_rcp(float v) { return __builtin_amdgcn_rcpf(v); }
__device__ __forceinline__ float softplus_f(float v) {
    return fmaxf(v, 0.0f) + __logf(1.0f + __expf(-fabsf(v)));
}
__device__ __forceinline__ float pk2f(float a, float b) {
    fp16x2 p = __builtin_amdgcn_cvt_pkrtz(a, b);   // v_cvt_pkrtz_f16_f32
    return __builtin_bit_cast(float, p);
}

// ---- prep: 24 fp16 A-operand fragments into d_ws (one block per fragment) ----
// fid 0..19: GEMM1 A = Wc^T (Wc[k][ch] = sum_m f_out_w[m][k]*in_proj_w[ch][m],
//   conv_w folded for ch in [64,144)). Ghost k=36 carries the fully-fused bias.
// fid 20..23: GEMM2 A = out_proj_w[m][k] * norm_w[k] (norm fold).
extern "C" __global__ void __launch_bounds__(64)
prep_kernel(const float* __restrict__ f_out_w, const float* __restrict__ f_out_b,
            const float* __restrict__ in_proj_w, const float* __restrict__ conv_w,
            const float* __restrict__ conv_b, const float* __restrict__ dt_bias,
            const float* __restrict__ norm_w, const float* __restrict__ out_proj_w,
            void* __restrict__ ws) {
    const int fid = blockIdx.x;
    const int L = threadIdx.x;
    const int c = L & 15, q = L >> 4;
    unsigned short* fr = (unsigned short*)ws;
    for (int j = 0; j < 8; ++j) {
        float val = 0.f;
        if (fid < 20) {
            const int t = fid >> 1, ks = fid & 1;
            int m;
            if (t < 8) {                            // z (t<4) / xh (t>=4) remap
                const int u = t & 3;
                m = ((t < 4) ? 0 : 64) +
                    8 * (c >> 2) + 4 * (u & 1) + (c & 3) + 32 * (u >> 1);
            } else if (t == 8) {                    // B/C interleave remap (R15)
                m = ((c & 1) ? 136 : 128) + 2 * (c >> 2) + ((c >> 1) & 1);
            } else {                                // dt: heads {q, q+4} per lane
                m = 144 + (c >> 2) + 4 * ((c & 3) >> 1);
            }
            const int k = ks * 32 + q * 8 + j;      // feature
            if (m < 152) {
                if (k < IN_DIM) {
                    float acc = 0.f;
                    for (int mm = 0; mm < 32; ++mm)
                        acc += f_out_w[mm * IN_DIM + k] * in_proj_w[m * 32 + mm];
                    if (m >= 64 && m < 144) acc *= conv_w[(m - 64) * 2 + 1];
                    val = acc;
                } else if (k == IN_DIM) {           // ghost-feature bias slot
                    float acc = 0.f;
                    for (int mm = 0; mm < 32; ++mm)
                        acc += f_out_b[mm] * in_proj_w[m * 32 + mm];
                    if (m >= 64 && m < 144)      val = acc * conv_w[(m - 64) * 2 + 1] + conv_b[m - 64];
                    else if (m >= 144)           val = acc + dt_bias[m - 144];
                    else                         val = acc;
                }
            }
        } else {
            const int mt = (fid - 20) >> 1, ks = (fid - 20) & 1;
            const int m = mt * 16 + c;              // out channel (<32)
            const int k = ks * 32 + q * 8 + j;      // y channel (<64)
            val = out_proj_w[m * 64 + k] * norm_w[k];
        }
        _Float16 h = (_Float16)val;
        fr[fid * 512 + L * 8 + j] = __builtin_bit_cast(unsigned short, h);
    }
}

// ---- main: transposed GEMMs; lane (c,q) owns row c of its 16-row tile ----
// R20 = R16 exactly — the session-best body (bench 156.4us, dispatch ~46us):
// y-in-register GEMM2 via channel remap, lane-local bc/scale, 0 bank
// conflicts, LDS 24.5KB, (256,3), BLOCKS=2048/4 tiles per wave.
// Session conclusions baked in:
//  - (256,4) / forced reg caps: spill cliff (R8/R10/R17) — natural alloc
//    ~160-170 unified regs is irreducible for this fusion.
//  - chain shortening (shuffles 17->6, LDS hop deleted): neutral — wall is
//    a latency equilibrium invariant to issue work (R13/R15/R16).
//  - pipelining either direction: spill or +4us (R12/R18).
//  - grid reshaping: neutral (R19).
// ~46us/dispatch is the structural plateau of this decomposition.
extern "C" __global__ void __launch_bounds__(256, 3)
mamba_mfma_kernel(const float* __restrict__ x,
                  const float* __restrict__ D_skip,
                  const void* __restrict__ ws,
                  float* __restrict__ out,
                  int tiles_per_wave) {
    __shared__ float4 ldsW[1536];                  // 24 KiB: 24 A-fragments, 16B-aligned
    const int lane = threadIdx.x & 63;
    const int wv   = threadIdx.x >> 6;
    const int c = lane & 15, q = lane >> 4;

    // cooperative stage of all 24 fragments: 24576 B / 256 thr = 6 float4 each
    {
        const float4* src = (const float4*)ws;
#pragma unroll
        for (int i = 0; i < 6; ++i)
            ldsW[threadIdx.x + 256 * i] = src[threadIdx.x + 256 * i];
    }

    // D_skip for this lane's two heads (q and q+4)
    const float dsk0 = D_skip[q];
    const float dsk1 = D_skip[q + 4];

    const long rowBase = (long)(blockIdx.x * 4 + wv) * tiles_per_wave * 16;
    const float* xrow = x + (rowBase + c) * (long)IN_DIM;

    float4 xa, xb, xct;
    {
        const float* p = xrow + q * 8;
        xa = *(const float4*)p;
        xb = *(const float4*)(p + 4);
        xct = (q == 0) ? *(const float4*)(xrow + 32) : make_float4(0.f, 0.f, 0.f, 0.f);
    }

    __syncthreads();                               // weights resident in LDS
    const char* Wb = (const char*)ldsW;

#pragma unroll 1
    for (int tile = 0; tile < tiles_per_wave; ++tile) {
        float4 na = xa, nb = xb, nc2 = xct;
        if (tile + 1 < tiles_per_wave) {
            const float* p = xrow + (size_t)(tile + 1) * 16 * IN_DIM + q * 8;
            na = *(const float4*)p;
            nb = *(const float4*)(p + 4);
            if (q == 0) nc2 = *(const float4*)(xrow + (size_t)(tile + 1) * 16 * IN_DIM + 32);
        }

        // B-operand from x, packed with v_cvt_pkrtz (2 floats/op); bit_cast keeps
        // everything in registers (unions here caused scratch spills in R6).
        float4 t0, t1;
        t0.x = pk2f(xa.x, xa.y);
        t0.y = pk2f(xa.z, xa.w);
        t0.z = pk2f(xb.x, xb.y);
        t0.w = pk2f(xb.z, xb.w);
        t1.x = pk2f(xct.x, xct.y);                  // xct already 0 for q!=0
        t1.y = pk2f(xct.z, xct.w);
        t1.z = (q == 0) ? pk2f(1.0f, 0.0f) : 0.0f;  // ghost feature -> bias
        t1.w = 0.0f;
        const half8 Bx0 = __builtin_bit_cast(half8, t0);
        const half8 Bx1 = __builtin_bit_cast(half8, t1);

        // ---- tiles 8 (B/C interleaved) and 9 (dt remapped) first ----
        floatx4 acc8, acc9;
        {
            const half8 c80 = *(const half8*)(Wb + (size_t)(16 * 64 + lane) * 16);
            const half8 c81 = *(const half8*)(Wb + (size_t)(17 * 64 + lane) * 16);
            const half8 c90 = *(const half8*)(Wb + (size_t)(18 * 64 + lane) * 16);
            const half8 c91 = *(const half8*)(Wb + (size_t)(19 * 64 + lane) * 16);
            floatx4 z4 = {0.f, 0.f, 0.f, 0.f};
            acc8 = __builtin_amdgcn_mfma_f32_16x16x32_f16(c80, Bx0, z4, 0, 0, 0);
            acc8 = __builtin_amdgcn_mfma_f32_16x16x32_f16(c81, Bx1, acc8, 0, 0, 0);
            acc9 = __builtin_amdgcn_mfma_f32_16x16x32_f16(c90, Bx0, z4, 0, 0, 0);
            acc9 = __builtin_amdgcn_mfma_f32_16x16x32_f16(c91, Bx1, acc9, 0, 0, 0);
        }

        // bc: in-lane silu(B[s])*silu(C[s]) pairs (s = 2q + {0,1}), then
        // xor16 + xor32 sum over the 4 q-lanes -> bc in ALL lanes. 2 shuffles.
        float part;
        {
            const float b0 = acc8[0], c0 = acc8[1], b1 = acc8[2], c1 = acc8[3];
            const float d0 = (1.0f + __expf(-b0)) * (1.0f + __expf(-c0));
            const float d1 = (1.0f + __expf(-b1)) * (1.0f + __expf(-c1));
            part = b0 * c0 * fast_rcp(d0) + b1 * c1 * fast_rcp(d1);
        }
        const float h1 = part + __shfl_xor(part, 16, 64);
        const float bc = h1 + __shfl_xor(h1, 32, 64);

        // per-head scale, lane-local: acc9[0] = dt head q, acc9[2] = head q+4
        const float sclH0 = __builtin_fmaf(softplus_f(acc9[0]), bc, dsk0);
        const float sclH1 = __builtin_fmaf(softplus_f(acc9[2]), bc, dsk1);

        // ---- z/xh pairs: 4 MFMAs per t, consumed immediately into By ----
        // tile t supplies y chs {8q + 4*(t&1) + r + 32*(t>>1)} (head q+4*(t>>1))
        // -> packed pk2f pairs land DIRECTLY in By0 (t=0,1) / By1 (t=2,3).
        float4 by0f, by1f;
        float ssum = 0.f;
#pragma unroll
        for (int t = 0; t < 4; ++t) {
            const half8 cz0 = *(const half8*)(Wb + (size_t)((t * 2 + 0) * 64 + lane) * 16);
            const half8 cz1 = *(const half8*)(Wb + (size_t)((t * 2 + 1) * 64 + lane) * 16);
            const half8 cx0 = *(const half8*)(Wb + (size_t)(((t + 4) * 2 + 0) * 64 + lane) * 16);
            const half8 cx1 = *(const half8*)(Wb + (size_t)(((t + 4) * 2 + 1) * 64 + lane) * 16);
            floatx4 z4 = {0.f, 0.f, 0.f, 0.f};
            floatx4 az = __builtin_amdgcn_mfma_f32_16x16x32_f16(cz0, Bx0, z4, 0, 0, 0);
            az = __builtin_amdgcn_mfma_f32_16x16x32_f16(cz1, Bx1, az, 0, 0, 0);
            floatx4 ax = __builtin_amdgcn_mfma_f32_16x16x32_f16(cx0, Bx0, z4, 0, 0, 0);
            ax = __builtin_amdgcn_mfma_f32_16x16x32_f16(cx1, Bx1, ax, 0, 0, 0);

            const float scl = (t < 2) ? sclH0 : sclH1;
            float v[4];
#pragma unroll
            for (int r = 0; r < 4; ++r) {
                const float zr = az[r], xh = ax[r];
                const float den = (1.0f + __expf(-zr)) * (1.0f + __expf(-xh));
                v[r] = zr * xh * scl * fast_rcp(den);
                ssum = __builtin_fmaf(v[r], v[r], ssum);
            }
            const float plo = pk2f(v[0], v[1]);
            const float phi = pk2f(v[2], v[3]);
            if (t == 0)      { by0f.x = plo; by0f.y = phi; }
            else if (t == 1) { by0f.z = plo; by0f.w = phi; }
            else if (t == 2) { by1f.x = plo; by1f.y = phi; }
            else             { by1f.z = plo; by1f.w = phi; }
        }
        const half8 By0 = __builtin_bit_cast(half8, by0f);
        const half8 By1 = __builtin_bit_cast(half8, by1f);

        // GEMM2 A-fragments (weights) + MFMAs — independent of the ssum chain,
        // so they overlap the reduction shuffles below.
        const half8 A300 = *(const half8*)(Wb + (size_t)(20 * 64 + lane) * 16);
        const half8 A301 = *(const half8*)(Wb + (size_t)(21 * 64 + lane) * 16);
        const half8 A310 = *(const half8*)(Wb + (size_t)(22 * 64 + lane) * 16);
        const half8 A311 = *(const half8*)(Wb + (size_t)(23 * 64 + lane) * 16);

        floatx4 z4 = {0.f, 0.f, 0.f, 0.f};
        floatx4 lg0 = __builtin_amdgcn_mfma_f32_16x16x32_f16(A300, By0, z4, 0, 0, 0);
        lg0 = __builtin_amdgcn_mfma_f32_16x16x32_f16(A301, By1, lg0, 0, 0, 0);
        floatx4 lg1 = __builtin_amdgcn_mfma_f32_16x16x32_f16(A310, By0, z4, 0, 0, 0);
        lg1 = __builtin_amdgcn_mfma_f32_16x16x32_f16(A311, By1, lg1, 0, 0, 0);

        float ssr = ssum + __shfl_xor(ssum, 16, 64);
        ssr += __shfl_xor(ssr, 32, 64);
        const float rs = __builtin_amdgcn_rsqf(__builtin_fmaf(ssr, 1.0f / 64.0f, 1e-5f));

        // softmax over 32 out-chs; max-pass skipped (|logit*rs| small, fp32-safe);
        // log2e folded into rs so each exp is a single v_exp_f32 after one mul.
        const float rs2 = rs * 1.44269504f;
        float e0[4], e1[4];
        float lsum = 0.f;
#pragma unroll
        for (int r = 0; r < 4; ++r) {
            e0[r] = __builtin_amdgcn_exp2f(lg0[r] * rs2);
            e1[r] = __builtin_amdgcn_exp2f(lg1[r] * rs2);
            lsum += e0[r] + e1[r];
        }
        lsum += __shfl_xor(lsum, 16, 64);
        lsum += __shfl_xor(lsum, 32, 64);
        const float inv = fast_rcp(lsum);

        const long orow = rowBase + (long)tile * 16 + c;
        *(float4*)(out + orow * 32 + 4 * q) =
            make_float4(e0[0] * inv, e0[1] * inv, e0[2] * inv, e0[3] * inv);
        *(float4*)(out + orow * 32 + 16 + 4 * q) =
            make_float4(e1[0] * inv, e1[1] * inv, e1[2] * inv, e1[3] * inv);

        xa = na; xb = nb; xct = nc2;
    }
}

extern "C" void kernel_launch(void* const* d_in, const int* in_sizes, int n_in,
                              void* d_out, int out_size, void* d_ws, size_t ws_size,
                              hipStream_t stream) {
    const float* x          = (const float*)d_in[0];
    const float* f_out_w    = (const float*)d_in[1];
    const float* f_out_b    = (const float*)d_in[2];
    const float* in_proj_w  = (const float*)d_in[3];
    const float* conv_w     = (const float*)d_in[4];
    const float* conv_b     = (const float*)d_in[5];
    const float* dt_bias    = (const float*)d_in[6];
    // d_in[7] = A_log — unused by the reference
    const float* D_skip     = (const float*)d_in[8];
    const float* norm_w     = (const float*)d_in[9];
    const float* out_proj_w = (const float*)d_in[10];
    float* out = (float*)d_out;

    const int n = in_sizes[0] / IN_DIM;                 // 524288
    const int tiles_per_wave = n / (BLOCKS * 4 * 16);   // 4

    hipLaunchKernelGGL(prep_kernel, dim3(24), dim3(64), 0, stream,
                       f_out_w, f_out_b, in_proj_w, conv_w, conv_b, dt_bias,
                       norm_w, out_proj_w, d_ws);
    hipLaunchKernelGGL(mamba_mfma_kernel, dim3(BLOCKS), dim3(256), 0, stream,
                       x, D_skip, d_ws, out, tiles_per_wave);
}